// Round 20
// baseline (72.456 us; speedup 1.0000x reference)
//
#include <hip/hip_runtime.h>
#include <hip/hip_bf16.h>

#define B_   2
#define L_   2048
#define C_   256
#define H_   8
#define DK_  32
#define HD_  256
#define RSQRT_DK 0.17677669529663687f  // 1/sqrt(32)

// Measurement round: K1's GEMM branch repeats REP_K1 times (idempotent) so
// gemm_qkv_fused surfaces above the ~40-45us harness fills in top-5 with
// counters.  True K1 time = (dur_us - 32.8) / (REP_K1 - 1).
#define REP_K1 8
#define REP_FENCE() asm volatile("" ::: "memory")

typedef __attribute__((ext_vector_type(8))) short bf16x8;
typedef __attribute__((ext_vector_type(4))) float f32x4;
typedef __attribute__((ext_vector_type(4))) unsigned int u32x4;

__device__ __forceinline__ unsigned short f2bf(float x) {
    unsigned int u = __float_as_uint(x);
    u += 0x7fffu + ((u >> 16) & 1u);
    return (unsigned short)(u >> 16);
}
__device__ __forceinline__ float bf2f(unsigned short h) {
    return __uint_as_float((unsigned int)h << 16);
}

// Packed split-bf16 conversion: (x0,x1) -> {hi pair, lo pair} (each one u32
// of 2 bf16).  __float22bfloat162_rn lowers to HW v_cvt_pk_bf16_f32 (RTNE).
__device__ __forceinline__ uint2 split2(float x0, float x1) {
    __hip_bfloat162 h2 = __float22bfloat162_rn(make_float2(x0, x1));
    unsigned hu; __builtin_memcpy(&hu, &h2, 4);
    const float e0 = __uint_as_float(hu << 16);
    const float e1 = __uint_as_float(hu & 0xffff0000u);
    __hip_bfloat162 l2 = __float22bfloat162_rn(make_float2(x0 - e0, x1 - e1));
    unsigned lu; __builtin_memcpy(&lu, &l2, 4);
    return make_uint2(hu, lu);
}
__device__ __forceinline__ bf16x8 as_bf16x8(u32x4 v) {
    bf16x8 r; __builtin_memcpy(&r, &v, 16); return r;
}

// LDS weight-slice layout (per 64x256 plane of shorts): row pitch 256 shorts
// (uniform bank base), 16B-chunk XOR swizzle -> b128 reads/writes at bank floor.
#define WT_IDX(n, k) (((n) << 8) + (((((k) >> 3) ^ ((n) & 7))) << 3) + ((k) & 7))

// Stage W cols [n0, n0+63], k 0..255 from fp32 into LDS planes as split-bf16
// [n][k] via packed converts.  512-thread variant: thread handles 4 chunks.
__device__ __forceinline__ void stage_wT_512(
    const float* __restrict__ W, int n0, int tid,
    short* __restrict__ WTh, short* __restrict__ WTl)
{
    const int n  = tid & 63;
    const int kc = tid >> 6;           // 0..7
    #pragma unroll
    for (int c8 = 0; c8 < 4; ++c8) {
        const int k0 = kc * 32 + c8 * 8;
        u32x4 hv, lv;
        #pragma unroll
        for (int e = 0; e < 4; ++e) {
            const float x0 = W[(size_t)(k0 + 2 * e)     * HD_ + n0 + n];
            const float x1 = W[(size_t)(k0 + 2 * e + 1) * HD_ + n0 + n];
            const uint2 hl = split2(x0, x1);
            hv[e] = hl.x; lv[e] = hl.y;
        }
        const int o = (n << 8) + ((((k0 >> 3) ^ (n & 7))) << 3);
        *reinterpret_cast<u32x4*>(&WTh[o]) = hv;
        *reinterpret_cast<u32x4*>(&WTl[o]) = lv;
    }
}

// Copy a pre-converted 64-col weight slice from global wT (hi at [n*256+k],
// lo at +65536) into swizzled LDS.  Pure coalesced bf16x8 copy (256 thr).
__device__ __forceinline__ void stage_wT_copy(
    const unsigned short* __restrict__ wTp, int n0, int tid,
    short* __restrict__ WTh, short* __restrict__ WTl)
{
    #pragma unroll
    for (int it = 0; it < 8; ++it) {
        const int c = tid + it * 256;      // chunk 0..2047
        const int n = c >> 5, k8 = c & 31;
        const size_t go = (size_t)(n0 + n) * 256 + k8 * 8;
        const int o = (n << 8) + ((k8 ^ (n & 7)) << 3);
        *reinterpret_cast<bf16x8*>(&WTh[o]) = *reinterpret_cast<const bf16x8*>(&wTp[go]);
        *reinterpret_cast<bf16x8*>(&WTl[o]) = *reinterpret_cast<const bf16x8*>(&wTp[65536 + go]);
    }
}

// ---------------------------------------------------------------------------
// K1: QKV projection, split-bf16 MFMA, self-contained.  512 thr = 8 waves,
// wave tile 16x64.  Grid (32, 13).  GEMM branch x REP_K1 (measurement).
// ---------------------------------------------------------------------------
__global__ __launch_bounds__(512) void gemm_qkv_fused(
    const float* __restrict__ qx, const float* __restrict__ kx, const float* __restrict__ vx,
    const float* __restrict__ WQ, const float* __restrict__ bQ,
    const float* __restrict__ WK, const float* __restrict__ bK,
    const float* __restrict__ WV, const float* __restrict__ bV,
    const float* __restrict__ WO, unsigned short* __restrict__ wT,
    float* __restrict__ q, float* __restrict__ k, float* __restrict__ v,
    float* __restrict__ part)
{
    const int bx = blockIdx.x;          // 0..31
    const int yy = blockIdx.y;          // 0..12
    const int tid = threadIdx.x;

    if (yy == 12) {
        if (tid < 256) {
            const int n  = bx * 8 + (tid >> 5);
            const int k8 = (tid & 31) * 8;
            u32x4 hv, lv;
            #pragma unroll
            for (int e = 0; e < 4; ++e) {
                const float x0 = WO[(size_t)(k8 + 2 * e)     * HD_ + n];
                const float x1 = WO[(size_t)(k8 + 2 * e + 1) * HD_ + n];
                const uint2 hl = split2(x0, x1);
                hv[e] = hl.x; lv[e] = hl.y;
            }
            *reinterpret_cast<u32x4*>(&wT[(size_t)n * 256 + k8])         = hv;
            *reinterpret_cast<u32x4*>(&wT[65536 + (size_t)n * 256 + k8]) = lv;
        }
        return;
    }

    const int proj = yy >> 2, nt = yy & 3;
    const float* A    = proj == 0 ? qx : (proj == 1 ? kx : vx);
    const float* W    = proj == 0 ? WQ : (proj == 1 ? WK : WV);
    const float* bias = proj == 0 ? bQ : (proj == 1 ? bK : bV);
    float* out        = proj == 0 ? q  : (proj == 1 ? k  : v);
    const int n0 = nt * 64;

    __shared__ short WTh[64 * 256];
    __shared__ short WTl[64 * 256];
    __shared__ float red[8][4][16];

    const int w  = tid >> 6;            // wave 0..7
    const int l  = tid & 63;
    const int lm = l & 15, lk8 = (l >> 4) * 8, cr = (l >> 4) * 4;
    const int R  = bx * 128 + w * 16;   // wave tile 16x64

    #pragma unroll 1
    for (int rep = 0; rep < REP_K1; ++rep) {

    stage_wT_512(W, n0, tid, WTh, WTl);
    __syncthreads();

    f32x4 acc[4];
    #pragma unroll
    for (int nf = 0; nf < 4; ++nf) acc[nf] = (f32x4){0.f, 0.f, 0.f, 0.f};

    float4 Ab[2][2];
    #define LOAD_A(buf, ks)                                                          \
    {                                                                                \
        const float* p0 = &A[(size_t)(R + lm) * C_ + (ks) * 32 + lk8];               \
        Ab[buf][0] = *reinterpret_cast<const float4*>(p0);                           \
        Ab[buf][1] = *reinterpret_cast<const float4*>(p0 + 4);                       \
    }
    LOAD_A(0, 0)
    LOAD_A(1, 1)

    #pragma unroll
    for (int ks = 0; ks < 8; ++ks) {
        const int cur = ks & 1;
        bf16x8 ah, al;
        {
            float4 v0 = Ab[cur][0], v1 = Ab[cur][1];
            u32x4 hq, lq;
            const uint2 r0 = split2(v0.x, v0.y);
            const uint2 r1 = split2(v0.z, v0.w);
            const uint2 r2 = split2(v1.x, v1.y);
            const uint2 r3 = split2(v1.z, v1.w);
            hq[0] = r0.x; lq[0] = r0.y;
            hq[1] = r1.x; lq[1] = r1.y;
            hq[2] = r2.x; lq[2] = r2.y;
            hq[3] = r3.x; lq[3] = r3.y;
            ah = as_bf16x8(hq);
            al = as_bf16x8(lq);
        }
        if (ks < 6) LOAD_A(cur, ks + 2)
        #pragma unroll
        for (int nf = 0; nf < 4; ++nf) {
            const int o = WT_IDX(nf * 16 + lm, ks * 32 + lk8);
            const bf16x8 b_h = *reinterpret_cast<const bf16x8*>(&WTh[o]);
            const bf16x8 b_l = *reinterpret_cast<const bf16x8*>(&WTl[o]);
            acc[nf] = __builtin_amdgcn_mfma_f32_16x16x32_bf16(ah, b_h, acc[nf], 0, 0, 0);
            acc[nf] = __builtin_amdgcn_mfma_f32_16x16x32_bf16(ah, b_l, acc[nf], 0, 0, 0);
            acc[nf] = __builtin_amdgcn_mfma_f32_16x16x32_bf16(al, b_h, acc[nf], 0, 0, 0);
        }
    }
    #undef LOAD_A

    // epilogue: bias + scatter to (B,H,L,DK)
    #pragma unroll
    for (int nf = 0; nf < 4; ++nf) {
        const int col = n0 + nf * 16 + lm;
        const int h = col >> 5, d = col & 31;
        const float bb = bias[col];
        #pragma unroll
        for (int r = 0; r < 4; ++r) {
            const int m = R + cr + r;
            const int b = m >> 11, lrow = m & (L_ - 1);
            out[((size_t)(b * H_ + h) * L_ + lrow) * DK_ + d] = acc[nf][r] + bb;
        }
    }

    // V column-sum partials (deterministic, per block = 128 rows x 64 cols)
    if (proj == 2) {
        float sl[4];
        #pragma unroll
        for (int nf = 0; nf < 4; ++nf) {
            float s = acc[nf][0] + acc[nf][1] + acc[nf][2] + acc[nf][3];
            s += __shfl_xor(s, 16);
            s += __shfl_xor(s, 32);
            sl[nf] = s;
        }
        if (l < 16) {
            #pragma unroll
            for (int nf = 0; nf < 4; ++nf) red[w][nf][l] = sl[nf];
        }
        __syncthreads();
        if (tid < 64) {
            const int nf = tid >> 4, lmm = tid & 15;
            float tot = 0.f;
            #pragma unroll
            for (int ww = 0; ww < 8; ++ww) tot += red[ww][nf][lmm];
            const int col = n0 + nf * 16 + lmm;
            tot += 128.f * bias[col];
            const int h = col >> 5, d = col & 31;
            const int bh = (bx >> 4) * H_ + h;       // block spans one b
            part[((size_t)bh * 32 + d) * 16 + (bx & 15)] = tot;
        }
    }
    __syncthreads();
    REP_FENCE();
    }   // rep loop
}

// ---------------------------------------------------------------------------
// K2: attention (round-17 structure, reverted from round-19 experiment).
//  Blocks 0..255   : interior rows, ONE ROW PER LANE, fully DIRECT loads.
//  Blocks 256..767 : global-row partials (bh, row-pair, 128-col chunk).
// 128 threads (2 waves) per block.  LDS ~1.3 KB -> high occupancy.
// ---------------------------------------------------------------------------
__global__ __launch_bounds__(128) void attn_main(
    const float* __restrict__ q, const float* __restrict__ k,
    const float* __restrict__ v, const float* __restrict__ part,
    float* __restrict__ pm, float* __restrict__ pZ, float* __restrict__ pzv,
    unsigned short* __restrict__ zh, unsigned short* __restrict__ zl)
{
    __shared__ float Sf[324];

    const int blk = blockIdx.x;
    const int t = threadIdx.x;

    if (blk < 256) {
        // ----------------- interior rows, per-lane, direct -----------------
        const int bh = blk >> 4, c = blk & 15;
        const int base = c * 128;
        const float* qb = q + (size_t)bh * L_ * DK_;
        const float* kb = k + (size_t)bh * L_ * DK_;
        const float* vb = v + (size_t)bh * L_ * DK_;
        float* vs_sh = Sf;

        if (t < 32) {
            const float4* pp = reinterpret_cast<const float4*>(&part[((size_t)bh * 32 + t) * 16]);
            float4 pa = pp[0], pb = pp[1], pc = pp[2], pd = pp[3];
            vs_sh[t] = pa.x + pa.y + pa.z + pa.w + pb.x + pb.y + pb.z + pb.w
                     + pc.x + pc.y + pc.z + pc.w + pd.x + pd.y + pd.z + pd.w;
        }
        __syncthreads();

        const int i = base + 1 + t;
        if (i <= L_ - 2) {
            float qr[32];
            {
                const float4* qp = reinterpret_cast<const float4*>(&qb[(size_t)i * DK_]);
                #pragma unroll
                for (int u2 = 0; u2 < 8; ++u2) {
                    float4 x = qp[u2];
                    qr[u2 * 4 + 0] = x.x; qr[u2 * 4 + 1] = x.y;
                    qr[u2 * 4 + 2] = x.z; qr[u2 * 4 + 3] = x.w;
                }
            }
            const int rows[5] = {0, i - 1, i, i + 1, L_ - 1};
            float sv[5];
            #pragma unroll
            for (int jj = 0; jj < 5; ++jj) {
                const float4* kp = reinterpret_cast<const float4*>(&kb[(size_t)rows[jj] * DK_]);
                float p = 0.f;
                #pragma unroll
                for (int u2 = 0; u2 < 8; ++u2) {
                    float4 kv = kp[u2];
                    p += qr[u2 * 4 + 0] * kv.x + qr[u2 * 4 + 1] * kv.y
                       + qr[u2 * 4 + 2] * kv.z + qr[u2 * 4 + 3] * kv.w;
                }
                sv[jj] = p * RSQRT_DK;
            }
            const bool v1 = (i != 1), v3 = (i != L_ - 2);
            float m = fmaxf(0.f, sv[0]);                 // zero fillers join the max
            m = fmaxf(m, sv[2]); m = fmaxf(m, sv[4]);
            if (v1) m = fmaxf(m, sv[1]);
            if (v3) m = fmaxf(m, sv[3]);
            float e[5];
            e[0] = __expf(sv[0] - m);
            e[1] = v1 ? __expf(sv[1] - m) : 0.f;
            e[2] = __expf(sv[2] - m);
            e[3] = v3 ? __expf(sv[3] - m) : 0.f;
            e[4] = __expf(sv[4] - m);
            const int ns = 3 + (int)v1 + (int)v3;
            const float e0 = __expf(-m);
            const float Z = e[0] + e[1] + e[2] + e[3] + e[4] + (float)(L_ - ns) * e0;
            const float rZ = 1.f / Z;
            const float f1 = v1 ? 1.f : 0.f, f3 = v3 ? 1.f : 0.f;

            const float4* vp0 = reinterpret_cast<const float4*>(&vb[0]);
            const float4* vp1 = reinterpret_cast<const float4*>(&vb[(size_t)rows[1] * DK_]);
            const float4* vp2 = reinterpret_cast<const float4*>(&vb[(size_t)i * DK_]);
            const float4* vp3 = reinterpret_cast<const float4*>(&vb[(size_t)rows[3] * DK_]);
            const float4* vp4 = reinterpret_cast<const float4*>(&vb[(size_t)(L_ - 1) * DK_]);

            u32x4 zhq[4], zlq[4];
            #pragma unroll
            for (int u2 = 0; u2 < 8; ++u2) {
                float4 x0 = vp0[u2], x1 = vp1[u2], x2 = vp2[u2], x3 = vp3[u2], x4 = vp4[u2];
                float a0[4] = {x0.x, x0.y, x0.z, x0.w};
                float a1[4] = {x1.x, x1.y, x1.z, x1.w};
                float a2[4] = {x2.x, x2.y, x2.z, x2.w};
                float a3[4] = {x3.x, x3.y, x3.z, x3.w};
                float a4[4] = {x4.x, x4.y, x4.z, x4.w};
                float zd4[4];
                #pragma unroll
                for (int e2 = 0; e2 < 4; ++e2) {
                    const int d = u2 * 4 + e2;
                    const float num = e[0] * a0[e2] + e[1] * a1[e2] + e[2] * a2[e2]
                                    + e[3] * a3[e2] + e[4] * a4[e2];
                    const float vp_ = a0[e2] + f1 * a1[e2] + a2[e2] + f3 * a3[e2] + a4[e2];
                    zd4[e2] = (num + e0 * (vs_sh[d] - vp_)) * rZ;
                }
                const uint2 p0 = split2(zd4[0], zd4[1]);
                const uint2 p1 = split2(zd4[2], zd4[3]);
                zhq[u2 >> 1][(u2 & 1) * 2 + 0] = p0.x;
                zhq[u2 >> 1][(u2 & 1) * 2 + 1] = p1.x;
                zlq[u2 >> 1][(u2 & 1) * 2 + 0] = p0.y;
                zlq[u2 >> 1][(u2 & 1) * 2 + 1] = p1.y;
            }
            const int b = bh >> 3, h = bh & 7;
            const size_t o = (size_t)(b * L_ + i) * HD_ + h * DK_;
            #pragma unroll
            for (int u4 = 0; u4 < 4; ++u4) {
                *reinterpret_cast<u32x4*>(&zh[o + u4 * 8]) = zhq[u4];
                *reinterpret_cast<u32x4*>(&zl[o + u4 * 8]) = zlq[u4];
            }
        }
    } else {
        // ----------------- global-row partials -----------------
        const int blk2 = blk - 256;                 // 0..511
        const int bh = blk2 >> 5;
        const int pair = (blk2 >> 4) & 1;
        const int chunk = blk2 & 15;
        const int r = pair ? (L_ - 1) : 0;
        const int j0 = chunk * 128;
        const float* qb = q + (size_t)bh * L_ * DK_;
        const float* kb = k + (size_t)bh * L_ * DK_;
        const float* vb = v + (size_t)bh * L_ * DK_;

        float* qs  = Sf;          // 32
        float* sc  = Sf + 32;     // 128
        float* red = Sf + 160;    // 4
        float* pzs = Sf + 192;    // 128

        if (t < 32) qs[t] = qb[(size_t)r * DK_ + t];
        __syncthreads();

        const int j = j0 + t;
        const float4* kr = reinterpret_cast<const float4*>(&kb[(size_t)j * DK_]);
        float p = 0.f;
        #pragma unroll
        for (int u = 0; u < 8; ++u) {
            float4 kv = kr[u];
            p += qs[u * 4 + 0] * kv.x + qs[u * 4 + 1] * kv.y
               + qs[u * 4 + 2] * kv.z + qs[u * 4 + 3] * kv.w;
        }
        p *= RSQRT_DK;

        float lm = p;
        #pragma unroll
        for (int off = 32; off; off >>= 1) lm = fmaxf(lm, __shfl_xor(lm, off, 64));
        if ((t & 63) == 0) red[t >> 6] = lm;
        __syncthreads();
        const float m = fmaxf(red[0], red[1]);

        const float e = __expf(p - m);
        sc[t] = e;
        float ls = e;
        #pragma unroll
        for (int off = 32; off; off >>= 1) ls += __shfl_xor(ls, off, 64);
        if ((t & 63) == 0) red[2 + (t >> 6)] = ls;
        __syncthreads();
        const float Zc = red[2] + red[3];

        const int d = t & 31, g = t >> 5;
        float acc = 0.f;
        #pragma unroll 4
        for (int jj = 0; jj < 32; ++jj)
            acc += sc[g * 32 + jj] * vb[(size_t)(j0 + g * 32 + jj) * DK_ + d];
        pzs[g * 32 + d] = acc;
        __syncthreads();
        if (g == 0) {
            const float s2 = pzs[d] + pzs[32 + d] + pzs[64 + d] + pzs[96 + d];
            pzv[(size_t)blk2 * 32 + d] = s2;
        }
        if (t == 0) { pm[blk2] = m; pZ[blk2] = Zc; }
    }
}

// ---------------------------------------------------------------------------
// K3: out = z @ WO + bO via split-bf16 MFMA; WO slice COPIED pre-converted
// from global wT + INLINE global-row combine (round-17 verbatim, 16 chunks).
// ---------------------------------------------------------------------------
__global__ __launch_bounds__(256) void gemm_out_fused(
    const unsigned short* __restrict__ zh_c, unsigned short* __restrict__ zh,
    unsigned short* __restrict__ zl,
    const float* __restrict__ pm, const float* __restrict__ pZ,
    const float* __restrict__ pzv,
    const unsigned short* __restrict__ wT, const float* __restrict__ bO,
    float* __restrict__ out)
{
    const int bx = blockIdx.x;          // 0..63
    const int nt = blockIdx.y;          // 0..3
    const int n0 = nt * 64;

    __shared__ short WTh[64 * 256];
    __shared__ short WTl[64 * 256];

    const int tid = threadIdx.x;
    stage_wT_copy(wT, n0, tid, WTh, WTl);

    // inline combine of global-row partials (16 x 128-col chunks per row)
    int zrow = -1;
    if      (bx == 0)  zrow = 0;
    else if (bx == 31) zrow = L_ - 1;
    else if (bx == 32) zrow = L_;
    else if (bx == 63) zrow = 2 * L_ - 1;
    if (zrow >= 0) {
        const int h = tid >> 5, d = tid & 31;
        const int b = zrow >> 11;
        const int r = zrow & (L_ - 1);
        const int pair = r ? 1 : 0;
        const int rowIdx = (b * H_ + h) * 2 + pair;
        const int base = rowIdx * 16;
        float m = -1e30f;
        #pragma unroll
        for (int c = 0; c < 16; ++c) m = fmaxf(m, pm[base + c]);
        float Z = 0.f, zd = 0.f;
        #pragma unroll
        for (int c = 0; c < 16; ++c) {
            const float w2 = __expf(pm[base + c] - m);
            Z  += pZ[base + c] * w2;
            zd += pzv[(size_t)(base + c) * 32 + d] * w2;
        }
        zd /= Z;
        const size_t o = (size_t)zrow * HD_ + h * DK_ + d;
        const unsigned short hb = f2bf(zd);
        zh[o] = hb;
        zl[o] = f2bf(zd - bf2f(hb));
    }
    __syncthreads();   // drains vmcnt: z stores complete before LOAD_Z below

    const int w  = tid >> 6;
    const int l  = tid & 63;
    const int lm = l & 15, lk8 = (l >> 4) * 8, cr = (l >> 4) * 4;
    const int R  = bx * 64 + w * 16;

    f32x4 acc[4];
    #pragma unroll
    for (int nf = 0; nf < 4; ++nf) acc[nf] = (f32x4){0.f, 0.f, 0.f, 0.f};

    bf16x8 Ah[2], Al[2];
    #define LOAD_Z(buf, ks)                                                          \
    {                                                                                \
        const size_t o = (size_t)(R + lm) * HD_ + (ks) * 32 + lk8;                   \
        Ah[buf] = *reinterpret_cast<const bf16x8*>(&zh_c[o]);                        \
        Al[buf] = *reinterpret_cast<const bf16x8*>(&zl[o]);                          \
    }
    LOAD_Z(0, 0)
    LOAD_Z(1, 1)

    #pragma unroll
    for (int ks = 0; ks < 8; ++ks) {
        const int cur = ks & 1;
        const bf16x8 a_h = Ah[cur], a_l = Al[cur];
        if (ks < 6) LOAD_Z(cur, ks + 2)
        #pragma unroll
        for (int nf = 0; nf < 4; ++nf) {
            const int o = WT_IDX(nf * 16 + lm, ks * 32 + lk8);
            const bf16x8 b_h = *reinterpret_cast<const bf16x8*>(&WTh[o]);
            const bf16x8 b_l = *reinterpret_cast<const bf16x8*>(&WTl[o]);
            acc[nf] = __builtin_amdgcn_mfma_f32_16x16x32_bf16(a_h, b_h, acc[nf], 0, 0, 0);
            acc[nf] = __builtin_amdgcn_mfma_f32_16x16x32_bf16(a_h, b_l, acc[nf], 0, 0, 0);
            acc[nf] = __builtin_amdgcn_mfma_f32_16x16x32_bf16(a_l, b_h, acc[nf], 0, 0, 0);
        }
    }
    #undef LOAD_Z

    #pragma unroll
    for (int nf = 0; nf < 4; ++nf) {
        const int col = n0 + nf * 16 + lm;
        const float bb = bO[col];
        #pragma unroll
        for (int r = 0; r < 4; ++r) {
            const int m = R + cr + r;
            out[(size_t)m * HD_ + col] = acc[nf][r] + bb;
        }
    }
}

// ---------------------------------------------------------------------------
extern "C" void kernel_launch(void* const* d_in, const int* in_sizes, int n_in,
                              void* d_out, int out_size, void* d_ws, size_t ws_size,
                              hipStream_t stream)
{
    const float* qx = (const float*)d_in[0];
    const float* kx = (const float*)d_in[1];
    const float* vx = (const float*)d_in[2];
    const float* WQ = (const float*)d_in[3];
    const float* bQ = (const float*)d_in[4];
    const float* WK = (const float*)d_in[5];
    const float* bK = (const float*)d_in[6];
    const float* WV = (const float*)d_in[7];
    const float* bV = (const float*)d_in[8];
    const float* WO = (const float*)d_in[9];
    const float* bO = (const float*)d_in[10];
    float* out = (float*)d_out;

    char* wsb = (char*)d_ws;
    float*          q    = (float*)(wsb);                            // 4 MB
    float*          k    = (float*)(wsb + (4u  << 20));              // 4 MB
    float*          v    = (float*)(wsb + (8u  << 20));              // 4 MB
    unsigned short* zh   = (unsigned short*)(wsb + (12u << 20));     // 2 MB
    unsigned short* zl   = (unsigned short*)(wsb + (14u << 20));     // 2 MB
    float*          part = (float*)(wsb + (16u << 20));              // 32 KB
    float*          pm   = (float*)(wsb + (16u << 20) + (1u << 16)); // 512 f
    float*          pZ   = pm + 512;
    float*          pzv  = pm + 1024;                                // 16384 f
    unsigned short* wT   = (unsigned short*)(wsb + (17u << 20));     // 256 KB

    gemm_qkv_fused<<<dim3(32, 13), 512, 0, stream>>>(qx, kx, vx, WQ, bQ, WK, bK, WV, bV, WO, wT, q, k, v, part);
    attn_main<<<768, 128, 0, stream>>>(q, k, v, part, pm, pZ, pzv, zh, zl);
    gemm_out_fused<<<dim3(64, 4), 256, 0, stream>>>(zh, zh, zl, pm, pZ, pzv, wT, bO, out);
}

// Round 21
// 33.344 us; speedup vs baseline: 2.1730x; 2.1730x over previous
//
#include <hip/hip_runtime.h>
#include <hip/hip_bf16.h>

#define B_   2
#define L_   2048
#define C_   256
#define H_   8
#define DK_  32
#define HD_  256
#define RSQRT_DK 0.17677669529663687f  // 1/sqrt(32)

typedef __attribute__((ext_vector_type(8))) short bf16x8;
typedef __attribute__((ext_vector_type(4))) float f32x4;
typedef __attribute__((ext_vector_type(4))) unsigned int u32x4;

__device__ __forceinline__ unsigned short f2bf(float x) {
    unsigned int u = __float_as_uint(x);
    u += 0x7fffu + ((u >> 16) & 1u);
    return (unsigned short)(u >> 16);
}
__device__ __forceinline__ float bf2f(unsigned short h) {
    return __uint_as_float((unsigned int)h << 16);
}

// Packed split-bf16 conversion: (x0,x1) -> {hi pair, lo pair} (each one u32
// of 2 bf16).  __float22bfloat162_rn lowers to HW v_cvt_pk_bf16_f32 (RTNE).
__device__ __forceinline__ uint2 split2(float x0, float x1) {
    __hip_bfloat162 h2 = __float22bfloat162_rn(make_float2(x0, x1));
    unsigned hu; __builtin_memcpy(&hu, &h2, 4);
    const float e0 = __uint_as_float(hu << 16);
    const float e1 = __uint_as_float(hu & 0xffff0000u);
    __hip_bfloat162 l2 = __float22bfloat162_rn(make_float2(x0 - e0, x1 - e1));
    unsigned lu; __builtin_memcpy(&lu, &l2, 4);
    return make_uint2(hu, lu);
}
__device__ __forceinline__ bf16x8 as_bf16x8(u32x4 v) {
    bf16x8 r; __builtin_memcpy(&r, &v, 16); return r;
}

// LDS weight-slice layout (per 64x256 plane of shorts): row pitch 256 shorts
// (uniform bank base), 16B-chunk XOR swizzle -> b128 reads/writes at bank floor.
#define WT_IDX(n, k) (((n) << 8) + (((((k) >> 3) ^ ((n) & 7))) << 3) + ((k) & 7))

// Stage W cols [n0, n0+63], k 0..255 from fp32 into LDS planes as split-bf16
// [n][k] via packed converts.  512-thread variant: thread handles 4 chunks.
__device__ __forceinline__ void stage_wT_512(
    const float* __restrict__ W, int n0, int tid,
    short* __restrict__ WTh, short* __restrict__ WTl)
{
    const int n  = tid & 63;
    const int kc = tid >> 6;           // 0..7
    #pragma unroll
    for (int c8 = 0; c8 < 4; ++c8) {
        const int k0 = kc * 32 + c8 * 8;
        u32x4 hv, lv;
        #pragma unroll
        for (int e = 0; e < 4; ++e) {
            const float x0 = W[(size_t)(k0 + 2 * e)     * HD_ + n0 + n];
            const float x1 = W[(size_t)(k0 + 2 * e + 1) * HD_ + n0 + n];
            const uint2 hl = split2(x0, x1);
            hv[e] = hl.x; lv[e] = hl.y;
        }
        const int o = (n << 8) + ((((k0 >> 3) ^ (n & 7))) << 3);
        *reinterpret_cast<u32x4*>(&WTh[o]) = hv;
        *reinterpret_cast<u32x4*>(&WTl[o]) = lv;
    }
}

// Copy a pre-converted 64-col weight slice from global wT (hi at [n*256+k],
// lo at +65536) into swizzled LDS.  Pure coalesced bf16x8 copy (256 thr).
__device__ __forceinline__ void stage_wT_copy(
    const unsigned short* __restrict__ wTp, int n0, int tid,
    short* __restrict__ WTh, short* __restrict__ WTl)
{
    #pragma unroll
    for (int it = 0; it < 8; ++it) {
        const int c = tid + it * 256;      // chunk 0..2047
        const int n = c >> 5, k8 = c & 31;
        const size_t go = (size_t)(n0 + n) * 256 + k8 * 8;
        const int o = (n << 8) + ((k8 ^ (n & 7)) << 3);
        *reinterpret_cast<bf16x8*>(&WTh[o]) = *reinterpret_cast<const bf16x8*>(&wTp[go]);
        *reinterpret_cast<bf16x8*>(&WTl[o]) = *reinterpret_cast<const bf16x8*>(&wTp[65536 + go]);
    }
}

// ---------------------------------------------------------------------------
// K1: QKV projection, split-bf16 MFMA, self-contained.  512 thr = 8 waves,
// wave tile 16x64.  DEEP A-PREFETCH: all 16 float4 A-loads issued upfront
// (48 outstanding vmem/lane with W staging) to hide cold HBM/L3 latency —
// round-20 REP counters showed K1 latency-bound (MFMA 24%, VALU 12%, HBM 4%).
// Grid (32, 13): yy 0..11 GEMM, yy 12 = WO -> wT convert for K3.
// ---------------------------------------------------------------------------
__global__ __launch_bounds__(512) void gemm_qkv_fused(
    const float* __restrict__ qx, const float* __restrict__ kx, const float* __restrict__ vx,
    const float* __restrict__ WQ, const float* __restrict__ bQ,
    const float* __restrict__ WK, const float* __restrict__ bK,
    const float* __restrict__ WV, const float* __restrict__ bV,
    const float* __restrict__ WO, unsigned short* __restrict__ wT,
    float* __restrict__ q, float* __restrict__ k, float* __restrict__ v,
    float* __restrict__ part)
{
    const int bx = blockIdx.x;          // 0..31
    const int yy = blockIdx.y;          // 0..12
    const int tid = threadIdx.x;

    if (yy == 12) {
        if (tid < 256) {
            const int n  = bx * 8 + (tid >> 5);
            const int k8 = (tid & 31) * 8;
            u32x4 hv, lv;
            #pragma unroll
            for (int e = 0; e < 4; ++e) {
                const float x0 = WO[(size_t)(k8 + 2 * e)     * HD_ + n];
                const float x1 = WO[(size_t)(k8 + 2 * e + 1) * HD_ + n];
                const uint2 hl = split2(x0, x1);
                hv[e] = hl.x; lv[e] = hl.y;
            }
            *reinterpret_cast<u32x4*>(&wT[(size_t)n * 256 + k8])         = hv;
            *reinterpret_cast<u32x4*>(&wT[65536 + (size_t)n * 256 + k8]) = lv;
        }
        return;
    }

    const int proj = yy >> 2, nt = yy & 3;
    const float* A    = proj == 0 ? qx : (proj == 1 ? kx : vx);
    const float* W    = proj == 0 ? WQ : (proj == 1 ? WK : WV);
    const float* bias = proj == 0 ? bQ : (proj == 1 ? bK : bV);
    float* out        = proj == 0 ? q  : (proj == 1 ? k  : v);
    const int n0 = nt * 64;

    __shared__ short WTh[64 * 256];
    __shared__ short WTl[64 * 256];
    __shared__ float red[8][4][16];

    const int w  = tid >> 6;            // wave 0..7
    const int l  = tid & 63;
    const int lm = l & 15, lk8 = (l >> 4) * 8, cr = (l >> 4) * 4;
    const int R  = bx * 128 + w * 16;   // wave tile 16x64

    // Deep prefetch: this lane's whole A strip (8 k-steps x 8 floats).
    float4 Aall[16];
    {
        const float* pA = &A[(size_t)(R + lm) * C_ + lk8];
        #pragma unroll
        for (int s = 0; s < 8; ++s) {
            Aall[2 * s]     = *reinterpret_cast<const float4*>(pA + s * 32);
            Aall[2 * s + 1] = *reinterpret_cast<const float4*>(pA + s * 32 + 4);
        }
    }

    stage_wT_512(W, n0, tid, WTh, WTl);
    __syncthreads();

    f32x4 acc[4];
    #pragma unroll
    for (int nf = 0; nf < 4; ++nf) acc[nf] = (f32x4){0.f, 0.f, 0.f, 0.f};

    #pragma unroll
    for (int ks = 0; ks < 8; ++ks) {
        bf16x8 ah, al;
        {
            float4 v0 = Aall[2 * ks], v1 = Aall[2 * ks + 1];
            u32x4 hq, lq;
            const uint2 r0 = split2(v0.x, v0.y);
            const uint2 r1 = split2(v0.z, v0.w);
            const uint2 r2 = split2(v1.x, v1.y);
            const uint2 r3 = split2(v1.z, v1.w);
            hq[0] = r0.x; lq[0] = r0.y;
            hq[1] = r1.x; lq[1] = r1.y;
            hq[2] = r2.x; lq[2] = r2.y;
            hq[3] = r3.x; lq[3] = r3.y;
            ah = as_bf16x8(hq);
            al = as_bf16x8(lq);
        }
        #pragma unroll
        for (int nf = 0; nf < 4; ++nf) {
            const int o = WT_IDX(nf * 16 + lm, ks * 32 + lk8);
            const bf16x8 b_h = *reinterpret_cast<const bf16x8*>(&WTh[o]);
            const bf16x8 b_l = *reinterpret_cast<const bf16x8*>(&WTl[o]);
            acc[nf] = __builtin_amdgcn_mfma_f32_16x16x32_bf16(ah, b_h, acc[nf], 0, 0, 0);
            acc[nf] = __builtin_amdgcn_mfma_f32_16x16x32_bf16(ah, b_l, acc[nf], 0, 0, 0);
            acc[nf] = __builtin_amdgcn_mfma_f32_16x16x32_bf16(al, b_h, acc[nf], 0, 0, 0);
        }
    }

    // epilogue: bias + scatter to (B,H,L,DK)
    #pragma unroll
    for (int nf = 0; nf < 4; ++nf) {
        const int col = n0 + nf * 16 + lm;
        const int h = col >> 5, d = col & 31;
        const float bb = bias[col];
        #pragma unroll
        for (int r = 0; r < 4; ++r) {
            const int m = R + cr + r;
            const int b = m >> 11, lrow = m & (L_ - 1);
            out[((size_t)(b * H_ + h) * L_ + lrow) * DK_ + d] = acc[nf][r] + bb;
        }
    }

    // V column-sum partials (deterministic, per block = 128 rows x 64 cols)
    if (proj == 2) {
        float sl[4];
        #pragma unroll
        for (int nf = 0; nf < 4; ++nf) {
            float s = acc[nf][0] + acc[nf][1] + acc[nf][2] + acc[nf][3];
            s += __shfl_xor(s, 16);
            s += __shfl_xor(s, 32);
            sl[nf] = s;
        }
        if (l < 16) {
            #pragma unroll
            for (int nf = 0; nf < 4; ++nf) red[w][nf][l] = sl[nf];
        }
        __syncthreads();
        if (tid < 64) {
            const int nf = tid >> 4, lmm = tid & 15;
            float tot = 0.f;
            #pragma unroll
            for (int ww = 0; ww < 8; ++ww) tot += red[ww][nf][lmm];
            const int col = n0 + nf * 16 + lmm;
            tot += 128.f * bias[col];
            const int h = col >> 5, d = col & 31;
            const int bh = (bx >> 4) * H_ + h;       // block spans one b
            part[((size_t)bh * 32 + d) * 16 + (bx & 15)] = tot;
        }
    }
}

// ---------------------------------------------------------------------------
// K2: attention (round-17 structure).
//  Blocks 0..255   : interior rows, ONE ROW PER LANE, fully DIRECT loads.
//  Blocks 256..767 : global-row partials (bh, row-pair, 128-col chunk).
// 128 threads (2 waves) per block.  LDS ~1.3 KB -> high occupancy.
// ---------------------------------------------------------------------------
__global__ __launch_bounds__(128) void attn_main(
    const float* __restrict__ q, const float* __restrict__ k,
    const float* __restrict__ v, const float* __restrict__ part,
    float* __restrict__ pm, float* __restrict__ pZ, float* __restrict__ pzv,
    unsigned short* __restrict__ zh, unsigned short* __restrict__ zl)
{
    __shared__ float Sf[324];

    const int blk = blockIdx.x;
    const int t = threadIdx.x;

    if (blk < 256) {
        // ----------------- interior rows, per-lane, direct -----------------
        const int bh = blk >> 4, c = blk & 15;
        const int base = c * 128;
        const float* qb = q + (size_t)bh * L_ * DK_;
        const float* kb = k + (size_t)bh * L_ * DK_;
        const float* vb = v + (size_t)bh * L_ * DK_;
        float* vs_sh = Sf;

        if (t < 32) {
            const float4* pp = reinterpret_cast<const float4*>(&part[((size_t)bh * 32 + t) * 16]);
            float4 pa = pp[0], pb = pp[1], pc = pp[2], pd = pp[3];
            vs_sh[t] = pa.x + pa.y + pa.z + pa.w + pb.x + pb.y + pb.z + pb.w
                     + pc.x + pc.y + pc.z + pc.w + pd.x + pd.y + pd.z + pd.w;
        }
        __syncthreads();

        const int i = base + 1 + t;
        if (i <= L_ - 2) {
            float qr[32];
            {
                const float4* qp = reinterpret_cast<const float4*>(&qb[(size_t)i * DK_]);
                #pragma unroll
                for (int u2 = 0; u2 < 8; ++u2) {
                    float4 x = qp[u2];
                    qr[u2 * 4 + 0] = x.x; qr[u2 * 4 + 1] = x.y;
                    qr[u2 * 4 + 2] = x.z; qr[u2 * 4 + 3] = x.w;
                }
            }
            const int rows[5] = {0, i - 1, i, i + 1, L_ - 1};
            float sv[5];
            #pragma unroll
            for (int jj = 0; jj < 5; ++jj) {
                const float4* kp = reinterpret_cast<const float4*>(&kb[(size_t)rows[jj] * DK_]);
                float p = 0.f;
                #pragma unroll
                for (int u2 = 0; u2 < 8; ++u2) {
                    float4 kv = kp[u2];
                    p += qr[u2 * 4 + 0] * kv.x + qr[u2 * 4 + 1] * kv.y
                       + qr[u2 * 4 + 2] * kv.z + qr[u2 * 4 + 3] * kv.w;
                }
                sv[jj] = p * RSQRT_DK;
            }
            const bool v1 = (i != 1), v3 = (i != L_ - 2);
            float m = fmaxf(0.f, sv[0]);                 // zero fillers join the max
            m = fmaxf(m, sv[2]); m = fmaxf(m, sv[4]);
            if (v1) m = fmaxf(m, sv[1]);
            if (v3) m = fmaxf(m, sv[3]);
            float e[5];
            e[0] = __expf(sv[0] - m);
            e[1] = v1 ? __expf(sv[1] - m) : 0.f;
            e[2] = __expf(sv[2] - m);
            e[3] = v3 ? __expf(sv[3] - m) : 0.f;
            e[4] = __expf(sv[4] - m);
            const int ns = 3 + (int)v1 + (int)v3;
            const float e0 = __expf(-m);
            const float Z = e[0] + e[1] + e[2] + e[3] + e[4] + (float)(L_ - ns) * e0;
            const float rZ = 1.f / Z;
            const float f1 = v1 ? 1.f : 0.f, f3 = v3 ? 1.f : 0.f;

            const float4* vp0 = reinterpret_cast<const float4*>(&vb[0]);
            const float4* vp1 = reinterpret_cast<const float4*>(&vb[(size_t)rows[1] * DK_]);
            const float4* vp2 = reinterpret_cast<const float4*>(&vb[(size_t)i * DK_]);
            const float4* vp3 = reinterpret_cast<const float4*>(&vb[(size_t)rows[3] * DK_]);
            const float4* vp4 = reinterpret_cast<const float4*>(&vb[(size_t)(L_ - 1) * DK_]);

            u32x4 zhq[4], zlq[4];
            #pragma unroll
            for (int u2 = 0; u2 < 8; ++u2) {
                float4 x0 = vp0[u2], x1 = vp1[u2], x2 = vp2[u2], x3 = vp3[u2], x4 = vp4[u2];
                float a0[4] = {x0.x, x0.y, x0.z, x0.w};
                float a1[4] = {x1.x, x1.y, x1.z, x1.w};
                float a2[4] = {x2.x, x2.y, x2.z, x2.w};
                float a3[4] = {x3.x, x3.y, x3.z, x3.w};
                float a4[4] = {x4.x, x4.y, x4.z, x4.w};
                float zd4[4];
                #pragma unroll
                for (int e2 = 0; e2 < 4; ++e2) {
                    const int d = u2 * 4 + e2;
                    const float num = e[0] * a0[e2] + e[1] * a1[e2] + e[2] * a2[e2]
                                    + e[3] * a3[e2] + e[4] * a4[e2];
                    const float vp_ = a0[e2] + f1 * a1[e2] + a2[e2] + f3 * a3[e2] + a4[e2];
                    zd4[e2] = (num + e0 * (vs_sh[d] - vp_)) * rZ;
                }
                const uint2 p0 = split2(zd4[0], zd4[1]);
                const uint2 p1 = split2(zd4[2], zd4[3]);
                zhq[u2 >> 1][(u2 & 1) * 2 + 0] = p0.x;
                zhq[u2 >> 1][(u2 & 1) * 2 + 1] = p1.x;
                zlq[u2 >> 1][(u2 & 1) * 2 + 0] = p0.y;
                zlq[u2 >> 1][(u2 & 1) * 2 + 1] = p1.y;
            }
            const int b = bh >> 3, h = bh & 7;
            const size_t o = (size_t)(b * L_ + i) * HD_ + h * DK_;
            #pragma unroll
            for (int u4 = 0; u4 < 4; ++u4) {
                *reinterpret_cast<u32x4*>(&zh[o + u4 * 8]) = zhq[u4];
                *reinterpret_cast<u32x4*>(&zl[o + u4 * 8]) = zlq[u4];
            }
        }
    } else {
        // ----------------- global-row partials -----------------
        const int blk2 = blk - 256;                 // 0..511
        const int bh = blk2 >> 5;
        const int pair = (blk2 >> 4) & 1;
        const int chunk = blk2 & 15;
        const int r = pair ? (L_ - 1) : 0;
        const int j0 = chunk * 128;
        const float* qb = q + (size_t)bh * L_ * DK_;
        const float* kb = k + (size_t)bh * L_ * DK_;
        const float* vb = v + (size_t)bh * L_ * DK_;

        float* qs  = Sf;          // 32
        float* sc  = Sf + 32;     // 128
        float* red = Sf + 160;    // 4
        float* pzs = Sf + 192;    // 128

        if (t < 32) qs[t] = qb[(size_t)r * DK_ + t];
        __syncthreads();

        const int j = j0 + t;
        const float4* kr = reinterpret_cast<const float4*>(&kb[(size_t)j * DK_]);
        float p = 0.f;
        #pragma unroll
        for (int u = 0; u < 8; ++u) {
            float4 kv = kr[u];
            p += qs[u * 4 + 0] * kv.x + qs[u * 4 + 1] * kv.y
               + qs[u * 4 + 2] * kv.z + qs[u * 4 + 3] * kv.w;
        }
        p *= RSQRT_DK;

        float lm = p;
        #pragma unroll
        for (int off = 32; off; off >>= 1) lm = fmaxf(lm, __shfl_xor(lm, off, 64));
        if ((t & 63) == 0) red[t >> 6] = lm;
        __syncthreads();
        const float m = fmaxf(red[0], red[1]);

        const float e = __expf(p - m);
        sc[t] = e;
        float ls = e;
        #pragma unroll
        for (int off = 32; off; off >>= 1) ls += __shfl_xor(ls, off, 64);
        if ((t & 63) == 0) red[2 + (t >> 6)] = ls;
        __syncthreads();
        const float Zc = red[2] + red[3];

        const int d = t & 31, g = t >> 5;
        float acc = 0.f;
        #pragma unroll 4
        for (int jj = 0; jj < 32; ++jj)
            acc += sc[g * 32 + jj] * vb[(size_t)(j0 + g * 32 + jj) * DK_ + d];
        pzs[g * 32 + d] = acc;
        __syncthreads();
        if (g == 0) {
            const float s2 = pzs[d] + pzs[32 + d] + pzs[64 + d] + pzs[96 + d];
            pzv[(size_t)blk2 * 32 + d] = s2;
        }
        if (t == 0) { pm[blk2] = m; pZ[blk2] = Zc; }
    }
}

// ---------------------------------------------------------------------------
// K3: out = z @ WO + bO via split-bf16 MFMA; WO slice COPIED pre-converted
// from global wT + INLINE global-row combine; z-loads deep-prefetched.
// Grid (64, 4), 256 thr = 4 waves; block tile 64x64.
// ---------------------------------------------------------------------------
__global__ __launch_bounds__(256) void gemm_out_fused(
    const unsigned short* __restrict__ zh_c, unsigned short* __restrict__ zh,
    unsigned short* __restrict__ zl,
    const float* __restrict__ pm, const float* __restrict__ pZ,
    const float* __restrict__ pzv,
    const unsigned short* __restrict__ wT, const float* __restrict__ bO,
    float* __restrict__ out)
{
    const int bx = blockIdx.x;          // 0..63
    const int nt = blockIdx.y;          // 0..3
    const int n0 = nt * 64;

    __shared__ short WTh[64 * 256];
    __shared__ short WTl[64 * 256];

    const int tid = threadIdx.x;
    stage_wT_copy(wT, n0, tid, WTh, WTl);

    // inline combine of global-row partials (16 x 128-col chunks per row)
    int zrow = -1;
    if      (bx == 0)  zrow = 0;
    else if (bx == 31) zrow = L_ - 1;
    else if (bx == 32) zrow = L_;
    else if (bx == 63) zrow = 2 * L_ - 1;
    if (zrow >= 0) {
        const int h = tid >> 5, d = tid & 31;
        const int b = zrow >> 11;
        const int r = zrow & (L_ - 1);
        const int pair = r ? 1 : 0;
        const int rowIdx = (b * H_ + h) * 2 + pair;
        const int base = rowIdx * 16;
        float m = -1e30f;
        #pragma unroll
        for (int c = 0; c < 16; ++c) m = fmaxf(m, pm[base + c]);
        float Z = 0.f, zd = 0.f;
        #pragma unroll
        for (int c = 0; c < 16; ++c) {
            const float w2 = __expf(pm[base + c] - m);
            Z  += pZ[base + c] * w2;
            zd += pzv[(size_t)(base + c) * 32 + d] * w2;
        }
        zd /= Z;
        const size_t o = (size_t)zrow * HD_ + h * DK_ + d;
        const unsigned short hb = f2bf(zd);
        zh[o] = hb;
        zl[o] = f2bf(zd - bf2f(hb));
    }
    __syncthreads();   // drains vmcnt: z stores complete before z loads below

    const int w  = tid >> 6;
    const int l  = tid & 63;
    const int lm = l & 15, lk8 = (l >> 4) * 8, cr = (l >> 4) * 4;
    const int R  = bx * 64 + w * 16;

    // deep prefetch of this lane's whole z strip (8 k-steps, hi+lo)
    bf16x8 Zh[8], Zl[8];
    {
        const size_t o0 = (size_t)(R + lm) * HD_ + lk8;
        #pragma unroll
        for (int s = 0; s < 8; ++s) {
            Zh[s] = *reinterpret_cast<const bf16x8*>(&zh_c[o0 + s * 32]);
            Zl[s] = *reinterpret_cast<const bf16x8*>(&zl[o0 + s * 32]);
        }
    }

    f32x4 acc[4];
    #pragma unroll
    for (int nf = 0; nf < 4; ++nf) acc[nf] = (f32x4){0.f, 0.f, 0.f, 0.f};

    #pragma unroll
    for (int ks = 0; ks < 8; ++ks) {
        const bf16x8 a_h = Zh[ks], a_l = Zl[ks];
        #pragma unroll
        for (int nf = 0; nf < 4; ++nf) {
            const int o = WT_IDX(nf * 16 + lm, ks * 32 + lk8);
            const bf16x8 b_h = *reinterpret_cast<const bf16x8*>(&WTh[o]);
            const bf16x8 b_l = *reinterpret_cast<const bf16x8*>(&WTl[o]);
            acc[nf] = __builtin_amdgcn_mfma_f32_16x16x32_bf16(a_h, b_h, acc[nf], 0, 0, 0);
            acc[nf] = __builtin_amdgcn_mfma_f32_16x16x32_bf16(a_h, b_l, acc[nf], 0, 0, 0);
            acc[nf] = __builtin_amdgcn_mfma_f32_16x16x32_bf16(a_l, b_h, acc[nf], 0, 0, 0);
        }
    }

    #pragma unroll
    for (int nf = 0; nf < 4; ++nf) {
        const int col = n0 + nf * 16 + lm;
        const float bb = bO[col];
        #pragma unroll
        for (int r = 0; r < 4; ++r) {
            const int m = R + cr + r;
            out[(size_t)m * HD_ + col] = acc[nf][r] + bb;
        }
    }
}

// ---------------------------------------------------------------------------
extern "C" void kernel_launch(void* const* d_in, const int* in_sizes, int n_in,
                              void* d_out, int out_size, void* d_ws, size_t ws_size,
                              hipStream_t stream)
{
    const float* qx = (const float*)d_in[0];
    const float* kx = (const float*)d_in[1];
    const float* vx = (const float*)d_in[2];
    const float* WQ = (const float*)d_in[3];
    const float* bQ = (const float*)d_in[4];
    const float* WK = (const float*)d_in[5];
    const float* bK = (const float*)d_in[6];
    const float* WV = (const float*)d_in[7];
    const float* bV = (const float*)d_in[8];
    const float* WO = (const float*)d_in[9];
    const float* bO = (const float*)d_in[10];
    float* out = (float*)d_out;

    char* wsb = (char*)d_ws;
    float*          q    = (float*)(wsb);                            // 4 MB
    float*          k    = (float*)(wsb + (4u  << 20));              // 4 MB
    float*          v    = (float*)(wsb + (8u  << 20));              // 4 MB
    unsigned short* zh   = (unsigned short*)(wsb + (12u << 20));     // 2 MB
    unsigned short* zl   = (unsigned short*)(wsb + (14u << 20));     // 2 MB
    float*          part = (float*)(wsb + (16u << 20));              // 32 KB
    float*          pm   = (float*)(wsb + (16u << 20) + (1u << 16)); // 512 f
    float*          pZ   = pm + 512;
    float*          pzv  = pm + 1024;                                // 16384 f
    unsigned short* wT   = (unsigned short*)(wsb + (17u << 20));     // 256 KB

    gemm_qkv_fused<<<dim3(32, 13), 512, 0, stream>>>(qx, kx, vx, WQ, bQ, WK, bK, WV, bV, WO, wT, q, k, v, part);
    attn_main<<<768, 128, 0, stream>>>(q, k, v, part, pm, pZ, pzv, zh, zl);
    gemm_out_fused<<<dim3(64, 4), 256, 0, stream>>>(zh, zh, zl, pm, pZ, pzv, wT, bO, out);
}

// Round 22
// 32.816 us; speedup vs baseline: 2.2080x; 1.0161x over previous
//
#include <hip/hip_runtime.h>
#include <hip/hip_bf16.h>

#define B_   2
#define L_   2048
#define C_   256
#define H_   8
#define DK_  32
#define HD_  256
#define RSQRT_DK 0.17677669529663687f  // 1/sqrt(32)

typedef __attribute__((ext_vector_type(8))) short bf16x8;
typedef __attribute__((ext_vector_type(4))) float f32x4;
typedef __attribute__((ext_vector_type(4))) unsigned int u32x4;

__device__ __forceinline__ unsigned short f2bf(float x) {
    unsigned int u = __float_as_uint(x);
    u += 0x7fffu + ((u >> 16) & 1u);
    return (unsigned short)(u >> 16);
}
__device__ __forceinline__ float bf2f(unsigned short h) {
    return __uint_as_float((unsigned int)h << 16);
}

// Packed split-bf16 conversion: (x0,x1) -> {hi pair, lo pair} (each one u32
// of 2 bf16).  __float22bfloat162_rn lowers to HW v_cvt_pk_bf16_f32 (RTNE).
__device__ __forceinline__ uint2 split2(float x0, float x1) {
    __hip_bfloat162 h2 = __float22bfloat162_rn(make_float2(x0, x1));
    unsigned hu; __builtin_memcpy(&hu, &h2, 4);
    const float e0 = __uint_as_float(hu << 16);
    const float e1 = __uint_as_float(hu & 0xffff0000u);
    __hip_bfloat162 l2 = __float22bfloat162_rn(make_float2(x0 - e0, x1 - e1));
    unsigned lu; __builtin_memcpy(&lu, &l2, 4);
    return make_uint2(hu, lu);
}
__device__ __forceinline__ bf16x8 as_bf16x8(u32x4 v) {
    bf16x8 r; __builtin_memcpy(&r, &v, 16); return r;
}

// LDS weight-slice layout (per 64x256 plane of shorts): row pitch 256 shorts
// (uniform bank base), 16B-chunk XOR swizzle -> b128 reads/writes at bank floor.
#define WT_IDX(n, k) (((n) << 8) + (((((k) >> 3) ^ ((n) & 7))) << 3) + ((k) & 7))

// Stage W cols [n0, n0+63], k 0..255 from fp32 into LDS planes as split-bf16
// [n][k] via packed converts.  512-thread variant: thread handles 4 chunks.
__device__ __forceinline__ void stage_wT_512(
    const float* __restrict__ W, int n0, int tid,
    short* __restrict__ WTh, short* __restrict__ WTl)
{
    const int n  = tid & 63;
    const int kc = tid >> 6;           // 0..7
    #pragma unroll
    for (int c8 = 0; c8 < 4; ++c8) {
        const int k0 = kc * 32 + c8 * 8;
        u32x4 hv, lv;
        #pragma unroll
        for (int e = 0; e < 4; ++e) {
            const float x0 = W[(size_t)(k0 + 2 * e)     * HD_ + n0 + n];
            const float x1 = W[(size_t)(k0 + 2 * e + 1) * HD_ + n0 + n];
            const uint2 hl = split2(x0, x1);
            hv[e] = hl.x; lv[e] = hl.y;
        }
        const int o = (n << 8) + ((((k0 >> 3) ^ (n & 7))) << 3);
        *reinterpret_cast<u32x4*>(&WTh[o]) = hv;
        *reinterpret_cast<u32x4*>(&WTl[o]) = lv;
    }
}

// Copy a pre-converted 64-col weight slice from global wT (hi at [n*256+k],
// lo at +65536) into swizzled LDS.  Pure coalesced bf16x8 copy (256 thr).
__device__ __forceinline__ void stage_wT_copy(
    const unsigned short* __restrict__ wTp, int n0, int tid,
    short* __restrict__ WTh, short* __restrict__ WTl)
{
    #pragma unroll
    for (int it = 0; it < 8; ++it) {
        const int c = tid + it * 256;      // chunk 0..2047
        const int n = c >> 5, k8 = c & 31;
        const size_t go = (size_t)(n0 + n) * 256 + k8 * 8;
        const int o = (n << 8) + ((k8 ^ (n & 7)) << 3);
        *reinterpret_cast<bf16x8*>(&WTh[o]) = *reinterpret_cast<const bf16x8*>(&wTp[go]);
        *reinterpret_cast<bf16x8*>(&WTl[o]) = *reinterpret_cast<const bf16x8*>(&wTp[65536 + go]);
    }
}

// ---------------------------------------------------------------------------
// K1: QKV projection, split-bf16 MFMA, self-contained.  512 thr = 8 waves,
// wave tile 16x64.  Grid (32, 13):
//  yy 0..11 : proj*4 + nt GEMM blocks (block tile 128x64), V col-sums.
//  yy 12    : convert WO (fp32 [k][n]) -> global wT split-bf16 [n][k] for K3.
// (round-17 verbatim — measured session best)
// ---------------------------------------------------------------------------
__global__ __launch_bounds__(512) void gemm_qkv_fused(
    const float* __restrict__ qx, const float* __restrict__ kx, const float* __restrict__ vx,
    const float* __restrict__ WQ, const float* __restrict__ bQ,
    const float* __restrict__ WK, const float* __restrict__ bK,
    const float* __restrict__ WV, const float* __restrict__ bV,
    const float* __restrict__ WO, unsigned short* __restrict__ wT,
    float* __restrict__ q, float* __restrict__ k, float* __restrict__ v,
    float* __restrict__ part)
{
    const int bx = blockIdx.x;          // 0..31
    const int yy = blockIdx.y;          // 0..12
    const int tid = threadIdx.x;

    if (yy == 12) {
        if (tid < 256) {
            const int n  = bx * 8 + (tid >> 5);
            const int k8 = (tid & 31) * 8;
            u32x4 hv, lv;
            #pragma unroll
            for (int e = 0; e < 4; ++e) {
                const float x0 = WO[(size_t)(k8 + 2 * e)     * HD_ + n];
                const float x1 = WO[(size_t)(k8 + 2 * e + 1) * HD_ + n];
                const uint2 hl = split2(x0, x1);
                hv[e] = hl.x; lv[e] = hl.y;
            }
            *reinterpret_cast<u32x4*>(&wT[(size_t)n * 256 + k8])         = hv;
            *reinterpret_cast<u32x4*>(&wT[65536 + (size_t)n * 256 + k8]) = lv;
        }
        return;
    }

    const int proj = yy >> 2, nt = yy & 3;
    const float* A    = proj == 0 ? qx : (proj == 1 ? kx : vx);
    const float* W    = proj == 0 ? WQ : (proj == 1 ? WK : WV);
    const float* bias = proj == 0 ? bQ : (proj == 1 ? bK : bV);
    float* out        = proj == 0 ? q  : (proj == 1 ? k  : v);
    const int n0 = nt * 64;

    __shared__ short WTh[64 * 256];
    __shared__ short WTl[64 * 256];
    __shared__ float red[8][4][16];

    stage_wT_512(W, n0, tid, WTh, WTl);
    __syncthreads();

    const int w  = tid >> 6;            // wave 0..7
    const int l  = tid & 63;
    const int lm = l & 15, lk8 = (l >> 4) * 8, cr = (l >> 4) * 4;
    const int R  = bx * 128 + w * 16;   // wave tile 16x64

    f32x4 acc[4];
    #pragma unroll
    for (int nf = 0; nf < 4; ++nf) acc[nf] = (f32x4){0.f, 0.f, 0.f, 0.f};

    float4 Ab[2][2];
    #define LOAD_A(buf, ks)                                                          \
    {                                                                                \
        const float* p0 = &A[(size_t)(R + lm) * C_ + (ks) * 32 + lk8];               \
        Ab[buf][0] = *reinterpret_cast<const float4*>(p0);                           \
        Ab[buf][1] = *reinterpret_cast<const float4*>(p0 + 4);                       \
    }
    LOAD_A(0, 0)
    LOAD_A(1, 1)

    #pragma unroll
    for (int ks = 0; ks < 8; ++ks) {
        const int cur = ks & 1;
        bf16x8 ah, al;
        {
            float4 v0 = Ab[cur][0], v1 = Ab[cur][1];
            u32x4 hq, lq;
            const uint2 r0 = split2(v0.x, v0.y);
            const uint2 r1 = split2(v0.z, v0.w);
            const uint2 r2 = split2(v1.x, v1.y);
            const uint2 r3 = split2(v1.z, v1.w);
            hq[0] = r0.x; lq[0] = r0.y;
            hq[1] = r1.x; lq[1] = r1.y;
            hq[2] = r2.x; lq[2] = r2.y;
            hq[3] = r3.x; lq[3] = r3.y;
            ah = as_bf16x8(hq);
            al = as_bf16x8(lq);
        }
        if (ks < 6) LOAD_A(cur, ks + 2)
        #pragma unroll
        for (int nf = 0; nf < 4; ++nf) {
            const int o = WT_IDX(nf * 16 + lm, ks * 32 + lk8);
            const bf16x8 b_h = *reinterpret_cast<const bf16x8*>(&WTh[o]);
            const bf16x8 b_l = *reinterpret_cast<const bf16x8*>(&WTl[o]);
            acc[nf] = __builtin_amdgcn_mfma_f32_16x16x32_bf16(ah, b_h, acc[nf], 0, 0, 0);
            acc[nf] = __builtin_amdgcn_mfma_f32_16x16x32_bf16(ah, b_l, acc[nf], 0, 0, 0);
            acc[nf] = __builtin_amdgcn_mfma_f32_16x16x32_bf16(al, b_h, acc[nf], 0, 0, 0);
        }
    }
    #undef LOAD_A

    // epilogue: bias + scatter to (B,H,L,DK)
    #pragma unroll
    for (int nf = 0; nf < 4; ++nf) {
        const int col = n0 + nf * 16 + lm;
        const int h = col >> 5, d = col & 31;
        const float bb = bias[col];
        #pragma unroll
        for (int r = 0; r < 4; ++r) {
            const int m = R + cr + r;
            const int b = m >> 11, lrow = m & (L_ - 1);
            out[((size_t)(b * H_ + h) * L_ + lrow) * DK_ + d] = acc[nf][r] + bb;
        }
    }

    // V column-sum partials (deterministic, per block = 128 rows x 64 cols)
    if (proj == 2) {
        float sl[4];
        #pragma unroll
        for (int nf = 0; nf < 4; ++nf) {
            float s = acc[nf][0] + acc[nf][1] + acc[nf][2] + acc[nf][3];
            s += __shfl_xor(s, 16);
            s += __shfl_xor(s, 32);
            sl[nf] = s;          // 16-row column sums, uniform over lanes w/ same lm
        }
        if (l < 16) {
            #pragma unroll
            for (int nf = 0; nf < 4; ++nf) red[w][nf][l] = sl[nf];
        }
        __syncthreads();
        if (tid < 64) {
            const int nf = tid >> 4, lmm = tid & 15;
            float tot = 0.f;
            #pragma unroll
            for (int ww = 0; ww < 8; ++ww) tot += red[ww][nf][lmm];
            const int col = n0 + nf * 16 + lmm;
            tot += 128.f * bias[col];
            const int h = col >> 5, d = col & 31;
            const int bh = (bx >> 4) * H_ + h;       // block spans one b
            part[((size_t)bh * 32 + d) * 16 + (bx & 15)] = tot;
        }
    }
}

// ---------------------------------------------------------------------------
// K2: attention (round-17 verbatim — measured session best).
//  Blocks 0..255   : interior rows, ONE ROW PER LANE, fully DIRECT loads.
//  Blocks 256..767 : global-row partials (bh, row-pair, 128-col chunk).
// 128 threads (2 waves) per block.  LDS ~1.3 KB -> high occupancy.
// ---------------------------------------------------------------------------
__global__ __launch_bounds__(128) void attn_main(
    const float* __restrict__ q, const float* __restrict__ k,
    const float* __restrict__ v, const float* __restrict__ part,
    float* __restrict__ pm, float* __restrict__ pZ, float* __restrict__ pzv,
    unsigned short* __restrict__ zh, unsigned short* __restrict__ zl)
{
    __shared__ float Sf[324];

    const int blk = blockIdx.x;
    const int t = threadIdx.x;

    if (blk < 256) {
        // ----------------- interior rows, per-lane, direct -----------------
        const int bh = blk >> 4, c = blk & 15;
        const int base = c * 128;
        const float* qb = q + (size_t)bh * L_ * DK_;
        const float* kb = k + (size_t)bh * L_ * DK_;
        const float* vb = v + (size_t)bh * L_ * DK_;
        float* vs_sh = Sf;

        if (t < 32) {
            const float4* pp = reinterpret_cast<const float4*>(&part[((size_t)bh * 32 + t) * 16]);
            float4 pa = pp[0], pb = pp[1], pc = pp[2], pd = pp[3];
            vs_sh[t] = pa.x + pa.y + pa.z + pa.w + pb.x + pb.y + pb.z + pb.w
                     + pc.x + pc.y + pc.z + pc.w + pd.x + pd.y + pd.z + pd.w;
        }
        __syncthreads();

        const int i = base + 1 + t;
        if (i <= L_ - 2) {
            float qr[32];
            {
                const float4* qp = reinterpret_cast<const float4*>(&qb[(size_t)i * DK_]);
                #pragma unroll
                for (int u2 = 0; u2 < 8; ++u2) {
                    float4 x = qp[u2];
                    qr[u2 * 4 + 0] = x.x; qr[u2 * 4 + 1] = x.y;
                    qr[u2 * 4 + 2] = x.z; qr[u2 * 4 + 3] = x.w;
                }
            }
            const int rows[5] = {0, i - 1, i, i + 1, L_ - 1};
            float sv[5];
            #pragma unroll
            for (int jj = 0; jj < 5; ++jj) {
                const float4* kp = reinterpret_cast<const float4*>(&kb[(size_t)rows[jj] * DK_]);
                float p = 0.f;
                #pragma unroll
                for (int u2 = 0; u2 < 8; ++u2) {
                    float4 kv = kp[u2];
                    p += qr[u2 * 4 + 0] * kv.x + qr[u2 * 4 + 1] * kv.y
                       + qr[u2 * 4 + 2] * kv.z + qr[u2 * 4 + 3] * kv.w;
                }
                sv[jj] = p * RSQRT_DK;
            }
            const bool v1 = (i != 1), v3 = (i != L_ - 2);
            float m = fmaxf(0.f, sv[0]);                 // zero fillers join the max
            m = fmaxf(m, sv[2]); m = fmaxf(m, sv[4]);
            if (v1) m = fmaxf(m, sv[1]);
            if (v3) m = fmaxf(m, sv[3]);
            float e[5];
            e[0] = __expf(sv[0] - m);
            e[1] = v1 ? __expf(sv[1] - m) : 0.f;
            e[2] = __expf(sv[2] - m);
            e[3] = v3 ? __expf(sv[3] - m) : 0.f;
            e[4] = __expf(sv[4] - m);
            const int ns = 3 + (int)v1 + (int)v3;
            const float e0 = __expf(-m);
            const float Z = e[0] + e[1] + e[2] + e[3] + e[4] + (float)(L_ - ns) * e0;
            const float rZ = 1.f / Z;
            const float f1 = v1 ? 1.f : 0.f, f3 = v3 ? 1.f : 0.f;

            const float4* vp0 = reinterpret_cast<const float4*>(&vb[0]);
            const float4* vp1 = reinterpret_cast<const float4*>(&vb[(size_t)rows[1] * DK_]);
            const float4* vp2 = reinterpret_cast<const float4*>(&vb[(size_t)i * DK_]);
            const float4* vp3 = reinterpret_cast<const float4*>(&vb[(size_t)rows[3] * DK_]);
            const float4* vp4 = reinterpret_cast<const float4*>(&vb[(size_t)(L_ - 1) * DK_]);

            u32x4 zhq[4], zlq[4];
            #pragma unroll
            for (int u2 = 0; u2 < 8; ++u2) {
                float4 x0 = vp0[u2], x1 = vp1[u2], x2 = vp2[u2], x3 = vp3[u2], x4 = vp4[u2];
                float a0[4] = {x0.x, x0.y, x0.z, x0.w};
                float a1[4] = {x1.x, x1.y, x1.z, x1.w};
                float a2[4] = {x2.x, x2.y, x2.z, x2.w};
                float a3[4] = {x3.x, x3.y, x3.z, x3.w};
                float a4[4] = {x4.x, x4.y, x4.z, x4.w};
                float zd4[4];
                #pragma unroll
                for (int e2 = 0; e2 < 4; ++e2) {
                    const int d = u2 * 4 + e2;
                    const float num = e[0] * a0[e2] + e[1] * a1[e2] + e[2] * a2[e2]
                                    + e[3] * a3[e2] + e[4] * a4[e2];
                    const float vp_ = a0[e2] + f1 * a1[e2] + a2[e2] + f3 * a3[e2] + a4[e2];
                    zd4[e2] = (num + e0 * (vs_sh[d] - vp_)) * rZ;
                }
                const uint2 p0 = split2(zd4[0], zd4[1]);
                const uint2 p1 = split2(zd4[2], zd4[3]);
                zhq[u2 >> 1][(u2 & 1) * 2 + 0] = p0.x;
                zhq[u2 >> 1][(u2 & 1) * 2 + 1] = p1.x;
                zlq[u2 >> 1][(u2 & 1) * 2 + 0] = p0.y;
                zlq[u2 >> 1][(u2 & 1) * 2 + 1] = p1.y;
            }
            const int b = bh >> 3, h = bh & 7;
            const size_t o = (size_t)(b * L_ + i) * HD_ + h * DK_;
            #pragma unroll
            for (int u4 = 0; u4 < 4; ++u4) {
                *reinterpret_cast<u32x4*>(&zh[o + u4 * 8]) = zhq[u4];
                *reinterpret_cast<u32x4*>(&zl[o + u4 * 8]) = zlq[u4];
            }
        }
    } else {
        // ----------------- global-row partials -----------------
        const int blk2 = blk - 256;                 // 0..511
        const int bh = blk2 >> 5;
        const int pair = (blk2 >> 4) & 1;
        const int chunk = blk2 & 15;
        const int r = pair ? (L_ - 1) : 0;
        const int j0 = chunk * 128;
        const float* qb = q + (size_t)bh * L_ * DK_;
        const float* kb = k + (size_t)bh * L_ * DK_;
        const float* vb = v + (size_t)bh * L_ * DK_;

        float* qs  = Sf;          // 32
        float* sc  = Sf + 32;     // 128
        float* red = Sf + 160;    // 4
        float* pzs = Sf + 192;    // 128

        if (t < 32) qs[t] = qb[(size_t)r * DK_ + t];
        __syncthreads();

        const int j = j0 + t;
        const float4* kr = reinterpret_cast<const float4*>(&kb[(size_t)j * DK_]);
        float p = 0.f;
        #pragma unroll
        for (int u = 0; u < 8; ++u) {
            float4 kv = kr[u];
            p += qs[u * 4 + 0] * kv.x + qs[u * 4 + 1] * kv.y
               + qs[u * 4 + 2] * kv.z + qs[u * 4 + 3] * kv.w;
        }
        p *= RSQRT_DK;

        float lm = p;
        #pragma unroll
        for (int off = 32; off; off >>= 1) lm = fmaxf(lm, __shfl_xor(lm, off, 64));
        if ((t & 63) == 0) red[t >> 6] = lm;
        __syncthreads();
        const float m = fmaxf(red[0], red[1]);

        const float e = __expf(p - m);
        sc[t] = e;
        float ls = e;
        #pragma unroll
        for (int off = 32; off; off >>= 1) ls += __shfl_xor(ls, off, 64);
        if ((t & 63) == 0) red[2 + (t >> 6)] = ls;
        __syncthreads();
        const float Zc = red[2] + red[3];

        const int d = t & 31, g = t >> 5;
        float acc = 0.f;
        #pragma unroll 4
        for (int jj = 0; jj < 32; ++jj)
            acc += sc[g * 32 + jj] * vb[(size_t)(j0 + g * 32 + jj) * DK_ + d];
        pzs[g * 32 + d] = acc;
        __syncthreads();
        if (g == 0) {
            const float s2 = pzs[d] + pzs[32 + d] + pzs[64 + d] + pzs[96 + d];
            pzv[(size_t)blk2 * 32 + d] = s2;
        }
        if (t == 0) { pm[blk2] = m; pZ[blk2] = Zc; }
    }
}

// ---------------------------------------------------------------------------
// K3: out = z @ WO + bO via split-bf16 MFMA; WO slice COPIED pre-converted
// from global wT + INLINE global-row combine (round-17 verbatim).
// Grid (64, 4), 256 thr = 4 waves; block tile 64x64.
// ---------------------------------------------------------------------------
__global__ __launch_bounds__(256) void gemm_out_fused(
    const unsigned short* __restrict__ zh_c, unsigned short* __restrict__ zh,
    unsigned short* __restrict__ zl,
    const float* __restrict__ pm, const float* __restrict__ pZ,
    const float* __restrict__ pzv,
    const unsigned short* __restrict__ wT, const float* __restrict__ bO,
    float* __restrict__ out)
{
    const int bx = blockIdx.x;          // 0..63
    const int nt = blockIdx.y;          // 0..3
    const int n0 = nt * 64;

    __shared__ short WTh[64 * 256];
    __shared__ short WTl[64 * 256];

    const int tid = threadIdx.x;
    stage_wT_copy(wT, n0, tid, WTh, WTl);

    // inline combine of global-row partials (was attn_g2_kernel)
    int zrow = -1;
    if      (bx == 0)  zrow = 0;
    else if (bx == 31) zrow = L_ - 1;
    else if (bx == 32) zrow = L_;
    else if (bx == 63) zrow = 2 * L_ - 1;
    if (zrow >= 0) {
        const int h = tid >> 5, d = tid & 31;
        const int b = zrow >> 11;
        const int r = zrow & (L_ - 1);
        const int pair = r ? 1 : 0;
        const int rowIdx = (b * H_ + h) * 2 + pair;
        const int base = rowIdx * 16;
        float m = -1e30f;
        #pragma unroll
        for (int c = 0; c < 16; ++c) m = fmaxf(m, pm[base + c]);
        float Z = 0.f, zd = 0.f;
        #pragma unroll
        for (int c = 0; c < 16; ++c) {
            const float w2 = __expf(pm[base + c] - m);
            Z  += pZ[base + c] * w2;
            zd += pzv[(size_t)(base + c) * 32 + d] * w2;
        }
        zd /= Z;
        const size_t o = (size_t)zrow * HD_ + h * DK_ + d;
        const unsigned short hb = f2bf(zd);
        zh[o] = hb;
        zl[o] = f2bf(zd - bf2f(hb));
    }
    __syncthreads();   // drains vmcnt: z stores complete before LOAD_Z below

    const int w  = tid >> 6;
    const int l  = tid & 63;
    const int lm = l & 15, lk8 = (l >> 4) * 8, cr = (l >> 4) * 4;
    const int R  = bx * 64 + w * 16;

    f32x4 acc[4];
    #pragma unroll
    for (int nf = 0; nf < 4; ++nf) acc[nf] = (f32x4){0.f, 0.f, 0.f, 0.f};

    bf16x8 Ah[2], Al[2];
    #define LOAD_Z(buf, ks)                                                          \
    {                                                                                \
        const size_t o = (size_t)(R + lm) * HD_ + (ks) * 32 + lk8;                   \
        Ah[buf] = *reinterpret_cast<const bf16x8*>(&zh_c[o]);                        \
        Al[buf] = *reinterpret_cast<const bf16x8*>(&zl[o]);                          \
    }
    LOAD_Z(0, 0)
    LOAD_Z(1, 1)

    #pragma unroll
    for (int ks = 0; ks < 8; ++ks) {
        const int cur = ks & 1;
        const bf16x8 a_h = Ah[cur], a_l = Al[cur];
        if (ks < 6) LOAD_Z(cur, ks + 2)
        #pragma unroll
        for (int nf = 0; nf < 4; ++nf) {
            const int o = WT_IDX(nf * 16 + lm, ks * 32 + lk8);
            const bf16x8 b_h = *reinterpret_cast<const bf16x8*>(&WTh[o]);
            const bf16x8 b_l = *reinterpret_cast<const bf16x8*>(&WTl[o]);
            acc[nf] = __builtin_amdgcn_mfma_f32_16x16x32_bf16(a_h, b_h, acc[nf], 0, 0, 0);
            acc[nf] = __builtin_amdgcn_mfma_f32_16x16x32_bf16(a_h, b_l, acc[nf], 0, 0, 0);
            acc[nf] = __builtin_amdgcn_mfma_f32_16x16x32_bf16(a_l, b_h, acc[nf], 0, 0, 0);
        }
    }
    #undef LOAD_Z

    #pragma unroll
    for (int nf = 0; nf < 4; ++nf) {
        const int col = n0 + nf * 16 + lm;
        const float bb = bO[col];
        #pragma unroll
        for (int r = 0; r < 4; ++r) {
            const int m = R + cr + r;
            out[(size_t)m * HD_ + col] = acc[nf][r] + bb;
        }
    }
}

// ---------------------------------------------------------------------------
extern "C" void kernel_launch(void* const* d_in, const int* in_sizes, int n_in,
                              void* d_out, int out_size, void* d_ws, size_t ws_size,
                              hipStream_t stream)
{
    const float* qx = (const float*)d_in[0];
    const float* kx = (const float*)d_in[1];
    const float* vx = (const float*)d_in[2];
    const float* WQ = (const float*)d_in[3];
    const float* bQ = (const float*)d_in[4];
    const float* WK = (const float*)d_in[5];
    const float* bK = (const float*)d_in[6];
    const float* WV = (const float*)d_in[7];
    const float* bV = (const float*)d_in[8];
    const float* WO = (const float*)d_in[9];
    const float* bO = (const float*)d_in[10];
    float* out = (float*)d_out;

    char* wsb = (char*)d_ws;
    float*          q    = (float*)(wsb);                            // 4 MB
    float*          k    = (float*)(wsb + (4u  << 20));              // 4 MB
    float*          v    = (float*)(wsb + (8u  << 20));              // 4 MB
    unsigned short* zh   = (unsigned short*)(wsb + (12u << 20));     // 2 MB
    unsigned short* zl   = (unsigned short*)(wsb + (14u << 20));     // 2 MB
    float*          part = (float*)(wsb + (16u << 20));              // 32 KB
    float*          pm   = (float*)(wsb + (16u << 20) + (1u << 16)); // 512 f
    float*          pZ   = pm + 512;
    float*          pzv  = pm + 1024;                                // 16384 f
    unsigned short* wT   = (unsigned short*)(wsb + (17u << 20));     // 256 KB

    gemm_qkv_fused<<<dim3(32, 13), 512, 0, stream>>>(qx, kx, vx, WQ, bQ, WK, bK, WV, bV, WO, wT, q, k, v, part);
    attn_main<<<768, 128, 0, stream>>>(q, k, v, part, pm, pZ, pzv, zh, zl);
    gemm_out_fused<<<dim3(64, 4), 256, 0, stream>>>(zh, zh, zl, pm, pZ, pzv, wT, bO, out);
}